// Round 4
// baseline (641.550 us; speedup 1.0000x reference)
//
#include <hip/hip_runtime.h>

// ---------------------------------------------------------------------------
// Decoder: fused cvt -> fused h0/c0 init GEMM -> gx GEMM -> ONE persistent
// cooperative kernel for all 32 LSTM steps -> one big FC GEMM.
// Round-3 found steps = 375us at ~11.7us/step = launch-overhead-bound.
// Persistent design: W_hh staged to LDS once, c in registers for all steps,
// h exchanged through the coherent point (sc0 sc1 write-through stores,
// sc0 sc1 L2-bypass loads), custom atomic barrier (NO L2 invalidate --
// that's what made cooperative grid.sync cost 60us/step in a prior session).
// ---------------------------------------------------------------------------

#define B_  64
#define T_  32
#define E_  512
#define H_  1024
#define V_  10000
#define F_  2048

typedef short short8 __attribute__((ext_vector_type(8)));
typedef float floatx4 __attribute__((ext_vector_type(4)));

__device__ __forceinline__ float bf2f(unsigned short u) {
  union { unsigned int i; float f; } c; c.i = ((unsigned int)u) << 16; return c.f;
}
__device__ __forceinline__ unsigned short f2bf(float f) {
  union { float f; unsigned int i; } c; c.f = f;
  unsigned int x = c.i;
  return (unsigned short)((x + 0x7fffu + ((x >> 16) & 1u)) >> 16);
}
__device__ __forceinline__ float sigmoidf_(float x) {
  return 1.0f / (1.0f + __expf(-x));
}
// async global->LDS, 16B per lane. LDS dest = wave-uniform base + lane*16.
__device__ __forceinline__ void gl_lds16(const unsigned short* g, unsigned short* l) {
  __builtin_amdgcn_global_load_lds(
      (const __attribute__((address_space(1))) unsigned int*)g,
      (__attribute__((address_space(3))) unsigned int*)l, 16, 0, 0);
}
// bijective XCD-chunked block remap (m204 formula; identity when nwg < 8)
__device__ __forceinline__ int xcd_swz(int lin, int nwg) {
  if (nwg < 8) return lin;
  int q = nwg >> 3, r = nwg & 7;
  int xcd = lin & 7, pos = lin >> 3;
  return (xcd < r ? xcd * (q + 1) : r * (q + 1) + (xcd - r) * q) + pos;
}

// ---------------- fused fp32 -> bf16 convert for all 6 arrays --------------
#define C_WIH  524288    // 4H*E/4
#define C_WHH  1048576   // 4H*H/4
#define C_WFC  2560000   // V*H/4
#define C_WI0  524288    // H*F/4
#define C_WC0  524288
#define C_FEA  32768     // B*F/4
#define C_TOT  (C_WIH + C_WHH + C_WFC + C_WI0 + C_WC0 + C_FEA)

__global__ __launch_bounds__(256) void cvt_all(
    const float* __restrict__ s0, const float* __restrict__ s1,
    const float* __restrict__ s2, const float* __restrict__ s3,
    const float* __restrict__ s4, const float* __restrict__ s5,
    unsigned short* __restrict__ d0, unsigned short* __restrict__ d1,
    unsigned short* __restrict__ d2, unsigned short* __restrict__ d3,
    unsigned short* __restrict__ d4, unsigned short* __restrict__ d5,
    unsigned int* __restrict__ bar) {
  // reset the persistent-kernel barrier counter at the coherent point
  if (blockIdx.x == 0 && threadIdx.x == 0)
    __hip_atomic_store(bar, 0u, __ATOMIC_RELAXED, __HIP_MEMORY_SCOPE_AGENT);
  int i = blockIdx.x * blockDim.x + threadIdx.x;
  int stride = gridDim.x * blockDim.x;
  for (; i < C_TOT; i += stride) {
    const float* s; unsigned short* d; int j = i;
    if (j < C_WIH)            { s = s0; d = d0; }
    else if ((j -= C_WIH) < C_WHH) { s = s1; d = d1; }
    else if ((j -= C_WHH) < C_WFC) { s = s2; d = d2; }
    else if ((j -= C_WFC) < C_WI0) { s = s3; d = d3; }
    else if ((j -= C_WI0) < C_WC0) { s = s4; d = d4; }
    else { j -= C_WC0; s = s5; d = d5; }
    float4 v = ((const float4*)s)[j];
    ushort4 o;
    o.x = f2bf(v.x); o.y = f2bf(v.y); o.z = f2bf(v.z); o.w = f2bf(v.w);
    ((ushort4*)d)[j] = o;
  }
}

// ---------------- embedding gather -> bf16, rows ordered (t*64+b) ----------
__global__ __launch_bounds__(128) void embed_gather(
    const float* __restrict__ table, const int* __restrict__ captions,
    unsigned short* __restrict__ out) {
  int row = blockIdx.x;            // row = t*B + b
  int t = row >> 6, b = row & 63;
  int idx = captions[b * T_ + t];
  const float4* src = (const float4*)(table + (size_t)idx * E_);
  ushort4* dst = (ushort4*)(out + (size_t)row * E_);
  for (int e = threadIdx.x; e < E_ / 4; e += blockDim.x) {
    float4 v = src[e];
    ushort4 o;
    o.x = f2bf(v.x); o.y = f2bf(v.y); o.z = f2bf(v.z); o.w = f2bf(v.w);
    dst[e] = o;
  }
}

// ---------------- 128x128 LDS-staged bf16 MFMA GEMM ------------------------
// C = act(A @ W^T + bias).  2-phase double-buffer, XOR bank swizzle,
// bijective XCD swizzle. OUT_INIT: N=2048 fused h0|c0 split epilogue.
template <int ACT_SIGMOID, int OUT_BF16, int OUT_INIT>
__global__ __launch_bounds__(256) void mfma_gemm128(
    const unsigned short* __restrict__ A, const unsigned short* __restrict__ W,
    const float* __restrict__ bias1, const float* __restrict__ bias2,
    void* __restrict__ out, void* __restrict__ out2, int M, int N, int K) {
  __shared__ unsigned short At[2][128 * 32];   // 16 KB
  __shared__ unsigned short Wt[2][128 * 32];   // 16 KB

  const int tid  = threadIdx.x;
  const int lane = tid & 63;
  const int wave = tid >> 6;
  const int l15  = lane & 15;
  const int quad = lane >> 4;
  const int wm   = (wave >> 1) * 64;
  const int wn   = (wave & 1) * 64;

  const int gx  = gridDim.x;
  const int nwg = gx * gridDim.y;
  const int wg  = xcd_swz(blockIdx.y * gx + blockIdx.x, nwg);
  const int m0  = (wg % gx) * 128;
  const int n0  = (wg / gx) * 128;
  const int ksl = (quad ^ (l15 & 3)) * 8;  // swizzled k-chunk for frag reads

  const int c0i = tid, c1i = tid + 256;
  const int ar0 = c0i >> 2, ak0 = (((c0i & 3) ^ (ar0 & 3)) * 8);
  const int ar1 = c1i >> 2, ak1 = (((c1i & 3) ^ (ar1 & 3)) * 8);
  int am0 = m0 + ar0; if (am0 > M - 1) am0 = M - 1;
  int am1 = m0 + ar1; if (am1 > M - 1) am1 = M - 1;
  int wn0 = n0 + ar0; if (wn0 > N - 1) wn0 = N - 1;
  int wn1 = n0 + ar1; if (wn1 > N - 1) wn1 = N - 1;
  const unsigned short* Ag0 = A + (size_t)am0 * K + ak0;
  const unsigned short* Ag1 = A + (size_t)am1 * K + ak1;
  const unsigned short* Wg0 = W + (size_t)wn0 * K + ak0;
  const unsigned short* Wg1 = W + (size_t)wn1 * K + ak1;

  floatx4 acc[4][4];
#pragma unroll
  for (int i = 0; i < 4; ++i)
#pragma unroll
    for (int j = 0; j < 4; ++j) acc[i][j] = (floatx4){0.f, 0.f, 0.f, 0.f};

  // prologue stage of k-tile 0 into buffer 0
  gl_lds16(Ag0, &At[0][c0i * 8]);
  gl_lds16(Ag1, &At[0][c1i * 8]);
  gl_lds16(Wg0, &Wt[0][c0i * 8]);
  gl_lds16(Wg1, &Wt[0][c1i * 8]);
  __syncthreads();

  int cur = 0;
  for (int k0 = 0; k0 < K; k0 += 32) {
    const int kn = k0 + 32;
    if (kn < K) {                      // issue next tile before compute
      const int nb = cur ^ 1;
      gl_lds16(Ag0 + kn, &At[nb][c0i * 8]);
      gl_lds16(Ag1 + kn, &At[nb][c1i * 8]);
      gl_lds16(Wg0 + kn, &Wt[nb][c0i * 8]);
      gl_lds16(Wg1 + kn, &Wt[nb][c1i * 8]);
    }
    short8 a[4], b[4];
#pragma unroll
    for (int mt = 0; mt < 4; ++mt)
      a[mt] = *(const short8*)&At[cur][(wm + mt * 16 + l15) * 32 + ksl];
#pragma unroll
    for (int nt = 0; nt < 4; ++nt)
      b[nt] = *(const short8*)&Wt[cur][(wn + nt * 16 + l15) * 32 + ksl];
#pragma unroll
    for (int mt = 0; mt < 4; ++mt)
#pragma unroll
      for (int nt = 0; nt < 4; ++nt)
        acc[mt][nt] = __builtin_amdgcn_mfma_f32_16x16x32_bf16(a[mt], b[nt], acc[mt][nt], 0, 0, 0);
    __syncthreads();                   // drains vmcnt: next tile resident
    cur ^= 1;
  }

#pragma unroll
  for (int nt = 0; nt < 4; ++nt) {
    int col = n0 + wn + nt * 16 + l15;
    if (col >= N) continue;
    float bsum;
    if (OUT_INIT)
      bsum = (col < H_) ? bias1[col] : bias2[col - H_];
    else
      bsum = (bias1 ? bias1[col] : 0.f) + (bias2 ? bias2[col] : 0.f);
#pragma unroll
    for (int mt = 0; mt < 4; ++mt) {
#pragma unroll
      for (int r = 0; r < 4; ++r) {
        int m = m0 + wm + mt * 16 + quad * 4 + r;
        if (m >= M) continue;
        float v = acc[mt][nt][r] + bsum;
        if (ACT_SIGMOID) v = sigmoidf_(v);
        if (OUT_INIT) {
          if (col < H_)
            ((unsigned short*)out)[(size_t)m * H_ + col] = f2bf(v);
          else
            ((float*)out2)[(size_t)m * H_ + (col - H_)] = v;
        } else if (OUT_BF16) {
          ((unsigned short*)out)[(size_t)m * N + col] = f2bf(v);
        } else {
          ((float*)out)[(size_t)m * N + col] = v;
        }
      }
    }
  }
}

// ---------------- persistent 32-step LSTM (cooperative, 256 blocks) --------
// Block = (colgroup cg of 8 h-cols, batch-half bh of 32). W_hh slab (64KB)
// staged to LDS ONCE; c lives in registers of the 128 cell threads for all
// 32 steps. Per step: h read via sc0sc1 L2-bypass loads (coherent point),
// 16 MFMAs/wave (kq x mt split), LDS reduce, cell math, h written via
// sc0sc1 write-through stores, then atomicAdd arrival + spin barrier
// (monotonic counter; no cache invalidate anywhere -> W_hh stays L2-hot).
#define WSPAD2 1032   // 1024 + 8 bf16 pad per row (granule spread)
__global__ __launch_bounds__(512, 2) void lstm_persistent(
    const unsigned short* __restrict__ W_hh_b,  // [4H,H] bf16
    const unsigned short* __restrict__ gx_b,    // [T,B,4H] bf16
    const float* __restrict__ c0_f32,           // [B,H] f32 initial c
    unsigned short* __restrict__ h_all,         // [(T+1),B,H] bf16
    unsigned int* __restrict__ bar) {           // barrier counter (reset=0)
  __shared__ unsigned short Ws[32 * WSPAD2];    // ~64.5 KB
  __shared__ float gbuf[4][32][33];             // ~16.9 KB

  const int tid  = threadIdx.x;
  const int lane = tid & 63;
  const int wave = tid >> 6;        // 0..7
  const int l15  = lane & 15;
  const int quad = lane >> 4;
  const int kb   = quad * 8;
  const int cg   = blockIdx.x >> 1; // col-group: cols [cg*8, cg*8+8)
  const int bh   = blockIdx.x & 1;  // batch half: batches [bh*32, bh*32+32)
  const int colbase = cg * 8;
  const int kq   = wave >> 1;       // K quarter: [kq*256, kq*256+256)
  const int mt   = wave & 1;        // batch frag: bh*32 + mt*16 .. +16

  // ---- one-time: stage 32 W_hh rows (gate-major n=g*8+j) as 64 1KB units --
#pragma unroll
  for (int it = 0; it < 8; ++it) {
    int u = wave * 8 + it;          // 0..63
    int n = u >> 1, half = u & 1;
    int grow = (n >> 3) * H_ + colbase + (n & 7);
    gl_lds16(W_hh_b + (size_t)grow * H_ + half * 512 + lane * 8,
             &Ws[n * WSPAD2 + half * 512]);
  }

  // ---- one-time: cell threads load initial c into registers ---------------
  const int bq = tid >> 2;          // 0..31 (batch in half), tid<128 only
  const int cp = tid & 3;           // col pair: cols 2cp, 2cp+1
  const int gb = bh * 32 + bq;
  float cA = 0.f, cB = 0.f;
  if (tid < 128) {
    float2 cv = *(const float2*)(c0_f32 + (size_t)gb * H_ + colbase + 2 * cp);
    cA = cv.x; cB = cv.y;
  }

  const unsigned short* hbase =
      h_all + (size_t)(bh * 32 + mt * 16 + l15) * H_ + kq * 256 + kb;
  const unsigned short* wb0 = &Ws[(size_t)(l15)      * WSPAD2 + kq * 256 + kb];
  const unsigned short* wb1 = &Ws[(size_t)(16 + l15) * WSPAD2 + kq * 256 + kb];

  __syncthreads();   // drains vmcnt: W staging complete

  for (int t = 0; t < T_; ++t) {
    // ---- h_t read: sc0 sc1 bypasses (possibly stale) local L2/L1 ----------
    const unsigned short* hp = hbase + (size_t)t * (B_ * H_);
    short8 hx[8];
#pragma unroll
    for (int i = 0; i < 8; ++i)
      asm volatile("global_load_dwordx4 %0, %1, off sc0 sc1"
                   : "=v"(hx[i]) : "v"(hp + i * 32) : "memory");

    // ---- gx for this step (normal loads; precomputed before launch) -------
    unsigned int ui = 0, uf = 0, ug = 0, uo = 0;
    if (tid < 128) {
      const unsigned short* gxp =
          gx_b + (size_t)t * (B_ * 4 * H_) + (size_t)gb * (4 * H_) + colbase + 2 * cp;
      ui = *(const unsigned int*)(gxp + 0 * H_);
      uf = *(const unsigned int*)(gxp + 1 * H_);
      ug = *(const unsigned int*)(gxp + 2 * H_);
      uo = *(const unsigned int*)(gxp + 3 * H_);
    }

    asm volatile("s_waitcnt vmcnt(0)" ::: "memory");
    __builtin_amdgcn_sched_barrier(0);   // rule#18: pin MFMA after the wait

    // ---- 16 MFMAs: 8 k-chunks x 2 row-frags -------------------------------
    floatx4 A0 = (floatx4){0.f, 0.f, 0.f, 0.f}, A1 = A0;
#pragma unroll
    for (int i = 0; i < 8; ++i) {
      short8 w0 = *(const short8*)(wb0 + i * 32);
      short8 w1 = *(const short8*)(wb1 + i * 32);
      A0 = __builtin_amdgcn_mfma_f32_16x16x32_bf16(hx[i], w0, A0, 0, 0, 0);
      A1 = __builtin_amdgcn_mfma_f32_16x16x32_bf16(hx[i], w1, A1, 0, 0, 0);
    }
#pragma unroll
    for (int r = 0; r < 4; ++r) {
      gbuf[kq][mt * 16 + quad * 4 + r][l15]      = A0[r];
      gbuf[kq][mt * 16 + quad * 4 + r][16 + l15] = A1[r];
    }
    __syncthreads();

    // ---- cell math: thread owns (batch gb, cols colbase+2cp, +1) ----------
    if (tid < 128) {
      const int c0c = 2 * cp, c1c = 2 * cp + 1;
      float giA = gbuf[0][bq][ 0 + c0c] + gbuf[1][bq][ 0 + c0c]
                + gbuf[2][bq][ 0 + c0c] + gbuf[3][bq][ 0 + c0c] + bf2f((unsigned short)(ui & 0xffff));
      float gfA = gbuf[0][bq][ 8 + c0c] + gbuf[1][bq][ 8 + c0c]
                + gbuf[2][bq][ 8 + c0c] + gbuf[3][bq][ 8 + c0c] + bf2f((unsigned short)(uf & 0xffff));
      float ggA = gbuf[0][bq][16 + c0c] + gbuf[1][bq][16 + c0c]
                + gbuf[2][bq][16 + c0c] + gbuf[3][bq][16 + c0c] + bf2f((unsigned short)(ug & 0xffff));
      float goA = gbuf[0][bq][24 + c0c] + gbuf[1][bq][24 + c0c]
                + gbuf[2][bq][24 + c0c] + gbuf[3][bq][24 + c0c] + bf2f((unsigned short)(uo & 0xffff));
      float giB = gbuf[0][bq][ 0 + c1c] + gbuf[1][bq][ 0 + c1c]
                + gbuf[2][bq][ 0 + c1c] + gbuf[3][bq][ 0 + c1c] + bf2f((unsigned short)(ui >> 16));
      float gfB = gbuf[0][bq][ 8 + c1c] + gbuf[1][bq][ 8 + c1c]
                + gbuf[2][bq][ 8 + c1c] + gbuf[3][bq][ 8 + c1c] + bf2f((unsigned short)(uf >> 16));
      float ggB = gbuf[0][bq][16 + c1c] + gbuf[1][bq][16 + c1c]
                + gbuf[2][bq][16 + c1c] + gbuf[3][bq][16 + c1c] + bf2f((unsigned short)(ug >> 16));
      float goB = gbuf[0][bq][24 + c1c] + gbuf[1][bq][24 + c1c]
                + gbuf[2][bq][24 + c1c] + gbuf[3][bq][24 + c1c] + bf2f((unsigned short)(uo >> 16));
      giA = sigmoidf_(giA); gfA = sigmoidf_(gfA); ggA = tanhf(ggA); goA = sigmoidf_(goA);
      giB = sigmoidf_(giB); gfB = sigmoidf_(gfB); ggB = tanhf(ggB); goB = sigmoidf_(goB);
      cA = gfA * cA + giA * ggA;
      cB = gfB * cB + giB * ggB;
      float hA = goA * tanhf(cA);
      float hB = goB * tanhf(cB);
      unsigned int hv = (unsigned int)f2bf(hA) | ((unsigned int)f2bf(hB) << 16);
      unsigned int* hop = (unsigned int*)(h_all + (size_t)(t + 1) * (B_ * H_)
                                          + (size_t)gb * H_ + colbase + 2 * cp);
      // write-through to coherent point so every XCD can read it next step
      asm volatile("global_store_dword %0, %1, off sc0 sc1"
                   :: "v"(hop), "v"(hv) : "memory");
      asm volatile("s_waitcnt vmcnt(0)" ::: "memory");
    }
    __syncthreads();   // all stores in this block acked at coherent point

    // ---- arrival + spin barrier (monotonic counter, no cache flush) -------
    if (t < T_ - 1) {
      if (tid == 0) {
        atomicAdd(bar, 1u);
        const unsigned int tgt = 256u * (unsigned int)(t + 1);
        while (__hip_atomic_load(bar, __ATOMIC_RELAXED, __HIP_MEMORY_SCOPE_AGENT) < tgt)
          __builtin_amdgcn_s_sleep(1);
      }
      __syncthreads();
    }
  }
}

// ---------------------------------------------------------------------------
extern "C" void kernel_launch(void* const* d_in, const int* in_sizes, int n_in,
                              void* d_out, int out_size, void* d_ws, size_t ws_size,
                              hipStream_t stream) {
  const float* features    = (const float*)d_in[0];
  const int*   captions    = (const int*)d_in[1];
  const float* embed_table = (const float*)d_in[2];
  const float* W_init_h    = (const float*)d_in[3];
  const float* b_init_h    = (const float*)d_in[4];
  const float* W_init_c    = (const float*)d_in[5];
  const float* b_init_c    = (const float*)d_in[6];
  const float* W_ih        = (const float*)d_in[7];
  const float* b_ih        = (const float*)d_in[8];
  const float* W_hh        = (const float*)d_in[9];
  const float* b_hh        = (const float*)d_in[10];
  const float* W_fc        = (const float*)d_in[11];
  const float* b_fc        = (const float*)d_in[12];
  float* out = (float*)d_out;

  // ---- workspace carve-up (bump allocator, 256B aligned) ----
  char* ws = (char*)d_ws;
  auto alloc = [&](size_t bytes) -> char* {
    char* p = ws;
    ws += (bytes + 255) & ~(size_t)255;
    return p;
  };
  unsigned short* W_ih_b  = (unsigned short*)alloc((size_t)4 * H_ * E_ * 2);
  unsigned short* W_hh_b  = (unsigned short*)alloc((size_t)4 * H_ * H_ * 2);
  unsigned short* W_fc_b  = (unsigned short*)alloc((size_t)V_ * H_ * 2);
  // NOTE: Wih0_b and Wic0_b must stay CONTIGUOUS (fused [2H,F] init GEMM).
  unsigned short* Wih0_b  = (unsigned short*)alloc((size_t)H_ * F_ * 2);
  unsigned short* Wic0_b  = (unsigned short*)alloc((size_t)H_ * F_ * 2);
  unsigned short* feat_b  = (unsigned short*)alloc((size_t)B_ * F_ * 2);
  unsigned short* emb_b   = (unsigned short*)alloc((size_t)T_ * B_ * E_ * 2);
  unsigned short* gx_b    = (unsigned short*)alloc((size_t)T_ * B_ * 4 * H_ * 2);
  unsigned short* h_all   = (unsigned short*)alloc((size_t)(T_ + 1) * B_ * H_ * 2);
  float*          c_f32   = (float*)alloc((size_t)B_ * H_ * 4);
  unsigned int*   bar     = (unsigned int*)alloc(256);
  (void)ws_size; (void)in_sizes; (void)n_in; (void)out_size; (void)Wic0_b;

  // ---- one fused fp32->bf16 conversion for all weights/features ----
  hipLaunchKernelGGL(cvt_all, dim3(4096), dim3(256), 0, stream,
                     W_ih, W_hh, W_fc, W_init_h, W_init_c, features,
                     W_ih_b, W_hh_b, W_fc_b, Wih0_b, Wic0_b, feat_b, bar);

  hipLaunchKernelGGL(embed_gather, dim3(T_ * B_), dim3(128), 0, stream,
                     embed_table, captions, emb_b);

  // ---- fused h0|c0 init: one GEMM over N=2048 (Wih0_b||Wic0_b contiguous) -
  hipLaunchKernelGGL((mfma_gemm128<0, 1, 1>), dim3(1, 2 * H_ / 128), dim3(256), 0, stream,
                     feat_b, Wih0_b, b_init_h, b_init_c,
                     (void*)h_all, (void*)c_f32, B_, 2 * H_, F_);

  // ---- gx = emb @ W_ih^T + b_ih + b_hh for all t ----
  hipLaunchKernelGGL((mfma_gemm128<0, 1, 0>), dim3(T_ * B_ / 128, 4 * H_ / 128), dim3(256), 0, stream,
                     emb_b, W_ih_b, b_ih, b_hh, (void*)gx_b, (void*)nullptr,
                     T_ * B_, 4 * H_, E_);

  // ---- all 32 recurrent steps in ONE cooperative persistent kernel --------
  {
    void* args[] = {(void*)&W_hh_b, (void*)&gx_b, (void*)&c_f32,
                    (void*)&h_all, (void*)&bar};
    hipLaunchCooperativeKernel((const void*)lstm_persistent,
                               dim3(2 * H_ / 8), dim3(512), args, 0, stream);
  }

  // ---- final FC: out = sigmoid(h_all[1..32] @ W_fc^T + b_fc) ----
  hipLaunchKernelGGL((mfma_gemm128<1, 0, 0>), dim3(T_ * B_ / 128, (V_ + 127) / 128), dim3(256), 0, stream,
                     h_all + (size_t)B_ * H_, W_fc_b, b_fc, (const float*)nullptr,
                     (void*)out, (void*)nullptr, T_ * B_, V_, H_);
}

// Round 5
// 483.663 us; speedup vs baseline: 1.3264x; 1.3264x over previous
//
#include <hip/hip_runtime.h>

// ---------------------------------------------------------------------------
// Decoder: fused cvt -> fused h0/c0 init GEMM -> gx GEMM -> ONE persistent
// kernel (regular launch, 256 blocks = 1/CU co-resident) for all 32 LSTM
// steps -> one big FC GEMM.
// Round-4 lessons: (a) cooperative launch costs ~220us/iter in drain overhead
// -- regular launch, residency by capacity (512thr, 83KB LDS, 88 VGPR =
// exactly 1 block/CU); (b) single-counter atomic barrier serializes 256 RMWs
// (~7us/step) -- replaced by per-block flag lines (no RMW) + wave-parallel
// ballot poll, split into two independent per-batch-half barriers.
// h exchange stays sc0sc1 write-through stores / L2-bypass loads (proven r4).
// ---------------------------------------------------------------------------

#define B_  64
#define T_  32
#define E_  512
#define H_  1024
#define V_  10000
#define F_  2048

typedef short short8 __attribute__((ext_vector_type(8)));
typedef float floatx4 __attribute__((ext_vector_type(4)));

__device__ __forceinline__ float bf2f(unsigned short u) {
  union { unsigned int i; float f; } c; c.i = ((unsigned int)u) << 16; return c.f;
}
__device__ __forceinline__ unsigned short f2bf(float f) {
  union { float f; unsigned int i; } c; c.f = f;
  unsigned int x = c.i;
  return (unsigned short)((x + 0x7fffu + ((x >> 16) & 1u)) >> 16);
}
__device__ __forceinline__ float sigmoidf_(float x) {
  return 1.0f / (1.0f + __expf(-x));
}
// async global->LDS, 16B per lane. LDS dest = wave-uniform base + lane*16.
__device__ __forceinline__ void gl_lds16(const unsigned short* g, unsigned short* l) {
  __builtin_amdgcn_global_load_lds(
      (const __attribute__((address_space(1))) unsigned int*)g,
      (__attribute__((address_space(3))) unsigned int*)l, 16, 0, 0);
}
// bijective XCD-chunked block remap (m204 formula; identity when nwg < 8)
__device__ __forceinline__ int xcd_swz(int lin, int nwg) {
  if (nwg < 8) return lin;
  int q = nwg >> 3, r = nwg & 7;
  int xcd = lin & 7, pos = lin >> 3;
  return (xcd < r ? xcd * (q + 1) : r * (q + 1) + (xcd - r) * q) + pos;
}

// ---------------- fused fp32 -> bf16 convert for all 6 arrays --------------
#define C_WIH  524288    // 4H*E/4
#define C_WHH  1048576   // 4H*H/4
#define C_WFC  2560000   // V*H/4
#define C_WI0  524288    // H*F/4
#define C_WC0  524288
#define C_FEA  32768     // B*F/4
#define C_TOT  (C_WIH + C_WHH + C_WFC + C_WI0 + C_WC0 + C_FEA)
#define NFLAGW 4096      // 256 flags x 16 dwords (one 64B line each)

__global__ __launch_bounds__(256) void cvt_all(
    const float* __restrict__ s0, const float* __restrict__ s1,
    const float* __restrict__ s2, const float* __restrict__ s3,
    const float* __restrict__ s4, const float* __restrict__ s5,
    unsigned short* __restrict__ d0, unsigned short* __restrict__ d1,
    unsigned short* __restrict__ d2, unsigned short* __restrict__ d3,
    unsigned short* __restrict__ d4, unsigned short* __restrict__ d5,
    unsigned int* __restrict__ flags) {
  // reset the persistent-kernel arrival flags (visible at coherent point via
  // end-of-kernel L2 writeback -- same path that publishes h0 to r4's reads)
  if (blockIdx.x == 0) {
    for (int w = threadIdx.x; w < NFLAGW; w += 256) flags[w] = 0u;
  }
  int i = blockIdx.x * blockDim.x + threadIdx.x;
  int stride = gridDim.x * blockDim.x;
  for (; i < C_TOT; i += stride) {
    const float* s; unsigned short* d; int j = i;
    if (j < C_WIH)            { s = s0; d = d0; }
    else if ((j -= C_WIH) < C_WHH) { s = s1; d = d1; }
    else if ((j -= C_WHH) < C_WFC) { s = s2; d = d2; }
    else if ((j -= C_WFC) < C_WI0) { s = s3; d = d3; }
    else if ((j -= C_WI0) < C_WC0) { s = s4; d = d4; }
    else { j -= C_WC0; s = s5; d = d5; }
    float4 v = ((const float4*)s)[j];
    ushort4 o;
    o.x = f2bf(v.x); o.y = f2bf(v.y); o.z = f2bf(v.z); o.w = f2bf(v.w);
    ((ushort4*)d)[j] = o;
  }
}

// ---------------- embedding gather -> bf16, rows ordered (t*64+b) ----------
__global__ __launch_bounds__(128) void embed_gather(
    const float* __restrict__ table, const int* __restrict__ captions,
    unsigned short* __restrict__ out) {
  int row = blockIdx.x;            // row = t*B + b
  int t = row >> 6, b = row & 63;
  int idx = captions[b * T_ + t];
  const float4* src = (const float4*)(table + (size_t)idx * E_);
  ushort4* dst = (ushort4*)(out + (size_t)row * E_);
  for (int e = threadIdx.x; e < E_ / 4; e += blockDim.x) {
    float4 v = src[e];
    ushort4 o;
    o.x = f2bf(v.x); o.y = f2bf(v.y); o.z = f2bf(v.z); o.w = f2bf(v.w);
    dst[e] = o;
  }
}

// ---------------- 128x128 LDS-staged bf16 MFMA GEMM ------------------------
// C = act(A @ W^T + bias).  2-phase double-buffer, XOR bank swizzle,
// bijective XCD swizzle. OUT_INIT: N=2048 fused h0|c0 split epilogue.
template <int ACT_SIGMOID, int OUT_BF16, int OUT_INIT>
__global__ __launch_bounds__(256) void mfma_gemm128(
    const unsigned short* __restrict__ A, const unsigned short* __restrict__ W,
    const float* __restrict__ bias1, const float* __restrict__ bias2,
    void* __restrict__ out, void* __restrict__ out2, int M, int N, int K) {
  __shared__ unsigned short At[2][128 * 32];   // 16 KB
  __shared__ unsigned short Wt[2][128 * 32];   // 16 KB

  const int tid  = threadIdx.x;
  const int lane = tid & 63;
  const int wave = tid >> 6;
  const int l15  = lane & 15;
  const int quad = lane >> 4;
  const int wm   = (wave >> 1) * 64;
  const int wn   = (wave & 1) * 64;

  const int gx  = gridDim.x;
  const int nwg = gx * gridDim.y;
  const int wg  = xcd_swz(blockIdx.y * gx + blockIdx.x, nwg);
  const int m0  = (wg % gx) * 128;
  const int n0  = (wg / gx) * 128;
  const int ksl = (quad ^ (l15 & 3)) * 8;  // swizzled k-chunk for frag reads

  const int c0i = tid, c1i = tid + 256;
  const int ar0 = c0i >> 2, ak0 = (((c0i & 3) ^ (ar0 & 3)) * 8);
  const int ar1 = c1i >> 2, ak1 = (((c1i & 3) ^ (ar1 & 3)) * 8);
  int am0 = m0 + ar0; if (am0 > M - 1) am0 = M - 1;
  int am1 = m0 + ar1; if (am1 > M - 1) am1 = M - 1;
  int wn0 = n0 + ar0; if (wn0 > N - 1) wn0 = N - 1;
  int wn1 = n0 + ar1; if (wn1 > N - 1) wn1 = N - 1;
  const unsigned short* Ag0 = A + (size_t)am0 * K + ak0;
  const unsigned short* Ag1 = A + (size_t)am1 * K + ak1;
  const unsigned short* Wg0 = W + (size_t)wn0 * K + ak0;
  const unsigned short* Wg1 = W + (size_t)wn1 * K + ak1;

  floatx4 acc[4][4];
#pragma unroll
  for (int i = 0; i < 4; ++i)
#pragma unroll
    for (int j = 0; j < 4; ++j) acc[i][j] = (floatx4){0.f, 0.f, 0.f, 0.f};

  // prologue stage of k-tile 0 into buffer 0
  gl_lds16(Ag0, &At[0][c0i * 8]);
  gl_lds16(Ag1, &At[0][c1i * 8]);
  gl_lds16(Wg0, &Wt[0][c0i * 8]);
  gl_lds16(Wg1, &Wt[0][c1i * 8]);
  __syncthreads();

  int cur = 0;
  for (int k0 = 0; k0 < K; k0 += 32) {
    const int kn = k0 + 32;
    if (kn < K) {                      // issue next tile before compute
      const int nb = cur ^ 1;
      gl_lds16(Ag0 + kn, &At[nb][c0i * 8]);
      gl_lds16(Ag1 + kn, &At[nb][c1i * 8]);
      gl_lds16(Wg0 + kn, &Wt[nb][c0i * 8]);
      gl_lds16(Wg1 + kn, &Wt[nb][c1i * 8]);
    }
    short8 a[4], b[4];
#pragma unroll
    for (int mt = 0; mt < 4; ++mt)
      a[mt] = *(const short8*)&At[cur][(wm + mt * 16 + l15) * 32 + ksl];
#pragma unroll
    for (int nt = 0; nt < 4; ++nt)
      b[nt] = *(const short8*)&Wt[cur][(wn + nt * 16 + l15) * 32 + ksl];
#pragma unroll
    for (int mt = 0; mt < 4; ++mt)
#pragma unroll
      for (int nt = 0; nt < 4; ++nt)
        acc[mt][nt] = __builtin_amdgcn_mfma_f32_16x16x32_bf16(a[mt], b[nt], acc[mt][nt], 0, 0, 0);
    __syncthreads();                   // drains vmcnt: next tile resident
    cur ^= 1;
  }

#pragma unroll
  for (int nt = 0; nt < 4; ++nt) {
    int col = n0 + wn + nt * 16 + l15;
    if (col >= N) continue;
    float bsum;
    if (OUT_INIT)
      bsum = (col < H_) ? bias1[col] : bias2[col - H_];
    else
      bsum = (bias1 ? bias1[col] : 0.f) + (bias2 ? bias2[col] : 0.f);
#pragma unroll
    for (int mt = 0; mt < 4; ++mt) {
#pragma unroll
      for (int r = 0; r < 4; ++r) {
        int m = m0 + wm + mt * 16 + quad * 4 + r;
        if (m >= M) continue;
        float v = acc[mt][nt][r] + bsum;
        if (ACT_SIGMOID) v = sigmoidf_(v);
        if (OUT_INIT) {
          if (col < H_)
            ((unsigned short*)out)[(size_t)m * H_ + col] = f2bf(v);
          else
            ((float*)out2)[(size_t)m * H_ + (col - H_)] = v;
        } else if (OUT_BF16) {
          ((unsigned short*)out)[(size_t)m * N + col] = f2bf(v);
        } else {
          ((float*)out)[(size_t)m * N + col] = v;
        }
      }
    }
  }
}

// ---------------- persistent 32-step LSTM (regular launch, 256 blocks) -----
// Block = (colgroup cg of 8 h-cols, batch-half bh of 32); exactly 1 block/CU
// (83KB LDS) -> all 256 co-resident without cooperative launch. W_hh slab
// staged to LDS once; c in registers for all steps. Per step: sc0sc1
// L2-bypass h loads, 16 MFMAs/wave, LDS reduce, cell math, sc0sc1
// write-through h stores, then CONTENTION-FREE barrier: per-block flag word
// in its own 64B line (plain store, no RMW), wave-0 ballot poll of the 128
// same-batch-half flags (2 bypass loads/lane). No cache invalidate anywhere.
#define WSPAD2 1032   // 1024 + 8 bf16 pad per row (granule spread)
__global__ __launch_bounds__(512, 2) void lstm_persistent(
    const unsigned short* __restrict__ W_hh_b,  // [4H,H] bf16
    const unsigned short* __restrict__ gx_b,    // [T,B,4H] bf16
    const float* __restrict__ c0_f32,           // [B,H] f32 initial c
    unsigned short* __restrict__ h_all,         // [(T+1),B,H] bf16
    unsigned int* __restrict__ flags) {         // 256 x 16-dword lines, =0
  __shared__ unsigned short Ws[32 * WSPAD2];    // ~64.5 KB
  __shared__ float gbuf[4][32][33];             // ~16.9 KB

  const int tid  = threadIdx.x;
  const int lane = tid & 63;
  const int wave = tid >> 6;        // 0..7
  const int l15  = lane & 15;
  const int quad = lane >> 4;
  const int kb   = quad * 8;
  const int bid  = blockIdx.x;
  const int cg   = bid >> 1;        // col-group: cols [cg*8, cg*8+8)
  const int bh   = bid & 1;         // batch half: batches [bh*32, bh*32+32)
  const int colbase = cg * 8;
  const int kq   = wave >> 1;       // K quarter: [kq*256, kq*256+256)
  const int mt   = wave & 1;        // batch frag: bh*32 + mt*16 .. +16

  // ---- one-time: stage 32 W_hh rows (gate-major n=g*8+j) as 64 1KB units --
#pragma unroll
  for (int it = 0; it < 8; ++it) {
    int u = wave * 8 + it;          // 0..63
    int n = u >> 1, half = u & 1;
    int grow = (n >> 3) * H_ + colbase + (n & 7);
    gl_lds16(W_hh_b + (size_t)grow * H_ + half * 512 + lane * 8,
             &Ws[n * WSPAD2 + half * 512]);
  }

  // ---- one-time: cell threads load initial c into registers ---------------
  const int bq = tid >> 2;          // 0..31 (batch in half), tid<128 only
  const int cp = tid & 3;           // col pair: cols 2cp, 2cp+1
  const int gb = bh * 32 + bq;
  float cA = 0.f, cB = 0.f;
  if (tid < 128) {
    float2 cv = *(const float2*)(c0_f32 + (size_t)gb * H_ + colbase + 2 * cp);
    cA = cv.x; cB = cv.y;
  }

  const unsigned short* hbase =
      h_all + (size_t)(bh * 32 + mt * 16 + l15) * H_ + kq * 256 + kb;
  const unsigned short* wb0 = &Ws[(size_t)(l15)      * WSPAD2 + kq * 256 + kb];
  const unsigned short* wb1 = &Ws[(size_t)(16 + l15) * WSPAD2 + kq * 256 + kb];
  // poll targets: the 128 same-bh flags; lane l checks set elements l, l+64
  const unsigned int* pf0 = flags + (size_t)(2 * lane        + bh) * 16;
  const unsigned int* pf1 = flags + (size_t)(2 * (lane + 64) + bh) * 16;

  __syncthreads();   // drains vmcnt: W staging complete

  for (int t = 0; t < T_; ++t) {
    // ---- h_t read: sc0 sc1 bypasses (possibly stale) local L2/L1 ----------
    const unsigned short* hp = hbase + (size_t)t * (B_ * H_);
    short8 hx[8];
#pragma unroll
    for (int i = 0; i < 8; ++i)
      asm volatile("global_load_dwordx4 %0, %1, off sc0 sc1"
                   : "=v"(hx[i]) : "v"(hp + i * 32) : "memory");

    // ---- gx for this step (normal loads; precomputed before launch) -------
    unsigned int ui = 0, uf = 0, ug = 0, uo = 0;
    if (tid < 128) {
      const unsigned short* gxp =
          gx_b + (size_t)t * (B_ * 4 * H_) + (size_t)gb * (4 * H_) + colbase + 2 * cp;
      ui = *(const unsigned int*)(gxp + 0 * H_);
      uf = *(const unsigned int*)(gxp + 1 * H_);
      ug = *(const unsigned int*)(gxp + 2 * H_);
      uo = *(const unsigned int*)(gxp + 3 * H_);
    }

    asm volatile("s_waitcnt vmcnt(0)" ::: "memory");
    __builtin_amdgcn_sched_barrier(0);   // rule#18: pin MFMA after the wait

    // ---- 16 MFMAs: 8 k-chunks x 2 row-frags -------------------------------
    floatx4 A0 = (floatx4){0.f, 0.f, 0.f, 0.f}, A1 = A0;
#pragma unroll
    for (int i = 0; i < 8; ++i) {
      short8 w0 = *(const short8*)(wb0 + i * 32);
      short8 w1 = *(const short8*)(wb1 + i * 32);
      A0 = __builtin_amdgcn_mfma_f32_16x16x32_bf16(hx[i], w0, A0, 0, 0, 0);
      A1 = __builtin_amdgcn_mfma_f32_16x16x32_bf16(hx[i], w1, A1, 0, 0, 0);
    }
#pragma unroll
    for (int r = 0; r < 4; ++r) {
      gbuf[kq][mt * 16 + quad * 4 + r][l15]      = A0[r];
      gbuf[kq][mt * 16 + quad * 4 + r][16 + l15] = A1[r];
    }
    __syncthreads();

    // ---- cell math: thread owns (batch gb, cols colbase+2cp, +1) ----------
    if (tid < 128) {
      const int c0c = 2 * cp, c1c = 2 * cp + 1;
      float giA = gbuf[0][bq][ 0 + c0c] + gbuf[1][bq][ 0 + c0c]
                + gbuf[2][bq][ 0 + c0c] + gbuf[3][bq][ 0 + c0c] + bf2f((unsigned short)(ui & 0xffff));
      float gfA = gbuf[0][bq][ 8 + c0c] + gbuf[1][bq][ 8 + c0c]
                + gbuf[2][bq][ 8 + c0c] + gbuf[3][bq][ 8 + c0c] + bf2f((unsigned short)(uf & 0xffff));
      float ggA = gbuf[0][bq][16 + c0c] + gbuf[1][bq][16 + c0c]
                + gbuf[2][bq][16 + c0c] + gbuf[3][bq][16 + c0c] + bf2f((unsigned short)(ug & 0xffff));
      float goA = gbuf[0][bq][24 + c0c] + gbuf[1][bq][24 + c0c]
                + gbuf[2][bq][24 + c0c] + gbuf[3][bq][24 + c0c] + bf2f((unsigned short)(uo & 0xffff));
      float giB = gbuf[0][bq][ 0 + c1c] + gbuf[1][bq][ 0 + c1c]
                + gbuf[2][bq][ 0 + c1c] + gbuf[3][bq][ 0 + c1c] + bf2f((unsigned short)(ui >> 16));
      float gfB = gbuf[0][bq][ 8 + c1c] + gbuf[1][bq][ 8 + c1c]
                + gbuf[2][bq][ 8 + c1c] + gbuf[3][bq][ 8 + c1c] + bf2f((unsigned short)(uf >> 16));
      float ggB = gbuf[0][bq][16 + c1c] + gbuf[1][bq][16 + c1c]
                + gbuf[2][bq][16 + c1c] + gbuf[3][bq][16 + c1c] + bf2f((unsigned short)(ug >> 16));
      float goB = gbuf[0][bq][24 + c1c] + gbuf[1][bq][24 + c1c]
                + gbuf[2][bq][24 + c1c] + gbuf[3][bq][24 + c1c] + bf2f((unsigned short)(uo >> 16));
      giA = sigmoidf_(giA); gfA = sigmoidf_(gfA); ggA = tanhf(ggA); goA = sigmoidf_(goA);
      giB = sigmoidf_(giB); gfB = sigmoidf_(gfB); ggB = tanhf(ggB); goB = sigmoidf_(goB);
      cA = gfA * cA + giA * ggA;
      cB = gfB * cB + giB * ggB;
      float hA = goA * tanhf(cA);
      float hB = goB * tanhf(cB);
      unsigned int hv = (unsigned int)f2bf(hA) | ((unsigned int)f2bf(hB) << 16);
      unsigned int* hop = (unsigned int*)(h_all + (size_t)(t + 1) * (B_ * H_)
                                          + (size_t)gb * H_ + colbase + 2 * cp);
      // write-through to coherent point so every XCD can read it next step
      asm volatile("global_store_dword %0, %1, off sc0 sc1"
                   :: "v"(hop), "v"(hv) : "memory");
      asm volatile("s_waitcnt vmcnt(0)" ::: "memory");
    }

    // ---- contention-free half-grid barrier --------------------------------
    if (t < T_ - 1) {
      __syncthreads();                 // all h stores of this block acked
      const unsigned int tgt = (unsigned int)(t + 1);
      if (tid == 0) {
        unsigned int* myf = flags + (size_t)bid * 16;
        asm volatile("global_store_dword %0, %1, off sc0 sc1"
                     :: "v"(myf), "v"(tgt) : "memory");
      }
      if (wave == 0) {
        unsigned int a, b;
        do {
          asm volatile("global_load_dword %0, %1, off sc0 sc1"
                       : "=v"(a) : "v"(pf0) : "memory");
          asm volatile("global_load_dword %0, %1, off sc0 sc1"
                       : "=v"(b) : "v"(pf1) : "memory");
          asm volatile("s_waitcnt vmcnt(0)" ::: "memory");
        } while (!__all(a >= tgt && b >= tgt));
      }
      __syncthreads();                 // release all waves into step t+1
    }
  }
}

// ---------------------------------------------------------------------------
extern "C" void kernel_launch(void* const* d_in, const int* in_sizes, int n_in,
                              void* d_out, int out_size, void* d_ws, size_t ws_size,
                              hipStream_t stream) {
  const float* features    = (const float*)d_in[0];
  const int*   captions    = (const int*)d_in[1];
  const float* embed_table = (const float*)d_in[2];
  const float* W_init_h    = (const float*)d_in[3];
  const float* b_init_h    = (const float*)d_in[4];
  const float* W_init_c    = (const float*)d_in[5];
  const float* b_init_c    = (const float*)d_in[6];
  const float* W_ih        = (const float*)d_in[7];
  const float* b_ih        = (const float*)d_in[8];
  const float* W_hh        = (const float*)d_in[9];
  const float* b_hh        = (const float*)d_in[10];
  const float* W_fc        = (const float*)d_in[11];
  const float* b_fc        = (const float*)d_in[12];
  float* out = (float*)d_out;

  // ---- workspace carve-up (bump allocator, 256B aligned) ----
  char* ws = (char*)d_ws;
  auto alloc = [&](size_t bytes) -> char* {
    char* p = ws;
    ws += (bytes + 255) & ~(size_t)255;
    return p;
  };
  unsigned short* W_ih_b  = (unsigned short*)alloc((size_t)4 * H_ * E_ * 2);
  unsigned short* W_hh_b  = (unsigned short*)alloc((size_t)4 * H_ * H_ * 2);
  unsigned short* W_fc_b  = (unsigned short*)alloc((size_t)V_ * H_ * 2);
  // NOTE: Wih0_b and Wic0_b must stay CONTIGUOUS (fused [2H,F] init GEMM).
  unsigned short* Wih0_b  = (unsigned short*)alloc((size_t)H_ * F_ * 2);
  unsigned short* Wic0_b  = (unsigned short*)alloc((size_t)H_ * F_ * 2);
  unsigned short* feat_b  = (unsigned short*)alloc((size_t)B_ * F_ * 2);
  unsigned short* emb_b   = (unsigned short*)alloc((size_t)T_ * B_ * E_ * 2);
  unsigned short* gx_b    = (unsigned short*)alloc((size_t)T_ * B_ * 4 * H_ * 2);
  unsigned short* h_all   = (unsigned short*)alloc((size_t)(T_ + 1) * B_ * H_ * 2);
  float*          c_f32   = (float*)alloc((size_t)B_ * H_ * 4);
  unsigned int*   flags   = (unsigned int*)alloc((size_t)NFLAGW * 4);
  (void)ws_size; (void)in_sizes; (void)n_in; (void)out_size; (void)Wic0_b;

  // ---- one fused fp32->bf16 conversion for all weights/features ----
  hipLaunchKernelGGL(cvt_all, dim3(4096), dim3(256), 0, stream,
                     W_ih, W_hh, W_fc, W_init_h, W_init_c, features,
                     W_ih_b, W_hh_b, W_fc_b, Wih0_b, Wic0_b, feat_b, flags);

  hipLaunchKernelGGL(embed_gather, dim3(T_ * B_), dim3(128), 0, stream,
                     embed_table, captions, emb_b);

  // ---- fused h0|c0 init: one GEMM over N=2048 (Wih0_b||Wic0_b contiguous) -
  hipLaunchKernelGGL((mfma_gemm128<0, 1, 1>), dim3(1, 2 * H_ / 128), dim3(256), 0, stream,
                     feat_b, Wih0_b, b_init_h, b_init_c,
                     (void*)h_all, (void*)c_f32, B_, 2 * H_, F_);

  // ---- gx = emb @ W_ih^T + b_ih + b_hh for all t ----
  hipLaunchKernelGGL((mfma_gemm128<0, 1, 0>), dim3(T_ * B_ / 128, 4 * H_ / 128), dim3(256), 0, stream,
                     emb_b, W_ih_b, b_ih, b_hh, (void*)gx_b, (void*)nullptr,
                     T_ * B_, 4 * H_, E_);

  // ---- all 32 recurrent steps in ONE persistent kernel (regular launch;
  //      256 blocks x 1/CU co-resident by capacity) ------------------------
  hipLaunchKernelGGL(lstm_persistent, dim3(2 * H_ / 8), dim3(512), 0, stream,
                     W_hh_b, gx_b, c_f32, h_all, flags);

  // ---- final FC: out = sigmoid(h_all[1..32] @ W_fc^T + b_fc) ----
  hipLaunchKernelGGL((mfma_gemm128<1, 0, 0>), dim3(T_ * B_ / 128, (V_ + 127) / 128), dim3(256), 0, stream,
                     h_all + (size_t)B_ * H_, W_fc_b, b_fc, (const float*)nullptr,
                     (void*)out, (void*)nullptr, T_ * B_, V_, H_);
}